// Round 1
// baseline (1447.178 us; speedup 1.0000x reference)
//
#include <hip/hip_runtime.h>
#include <stdint.h>

#define T_TOKENS 4096
#define D_DIM 768
#define H_DIM 1536
#define NEXP 64
#define TOPK 6
#define CAP 1536
#define MAXTILES 288          // bound: (24576 + 64*127 + 4096)/128 = 287.5
#define MAXROWS (MAXTILES*128)

typedef __bf16 bf16x8 __attribute__((ext_vector_type(8)));
typedef float f32x4 __attribute__((ext_vector_type(4)));

__device__ __forceinline__ ushort f2bf(float f) {
    union { float f; uint32_t u; } v; v.f = f;
    uint32_t r = v.u + 0x7FFFu + ((v.u >> 16) & 1u);   // RNE
    return (ushort)(r >> 16);
}

__device__ __forceinline__ uint32_t pkbf(float lo, float hi) {
    return (uint32_t)f2bf(lo) | ((uint32_t)f2bf(hi) << 16);
}

// ---------------------------------------------------------------- gate ------
__global__ __launch_bounds__(256)
void gate_kernel(const float* __restrict__ x, const float* __restrict__ gate_w,
                 int* __restrict__ cnt, float* __restrict__ prob_sum,
                 int* __restrict__ tok_of, float* __restrict__ sc_of)
{
    __shared__ float xs[16 * 768];
    __shared__ float sred[4][64];
    const int tid = threadIdx.x;
    const int t0 = blockIdx.x * 16;
    const float4* xg = (const float4*)(x + (size_t)t0 * 768);
    float4* xs4w = (float4*)xs;
    #pragma unroll
    for (int c = 0; c < 12; ++c) xs4w[c * 256 + tid] = xg[c * 256 + tid];
    __syncthreads();
    const int lane = tid & 63;
    const int wv = tid >> 6;
    float dots[4] = {0.f, 0.f, 0.f, 0.f};
    const float4* w4 = (const float4*)(gate_w + (size_t)lane * 768);
    const float4* xs4 = (const float4*)xs;
    for (int d = 0; d < 192; ++d) {
        float4 w = w4[d];
        #pragma unroll
        for (int tt = 0; tt < 4; ++tt) {
            float4 xv = xs4[(wv * 4 + tt) * 192 + d];
            dots[tt] += w.x * xv.x + w.y * xv.y + w.z * xv.z + w.w * xv.w;
        }
    }
    float psum_local = 0.f;
    for (int tt = 0; tt < 4; ++tt) {
        const int t = t0 + wv * 4 + tt;
        float z = dots[tt];
        float m = z;
        #pragma unroll
        for (int off = 32; off; off >>= 1) m = fmaxf(m, __shfl_xor(m, off));
        float ex = expf(z - m);
        float s = ex;
        #pragma unroll
        for (int off = 32; off; off >>= 1) s += __shfl_xor(s, off);
        float p = ex / s;
        psum_local += p;
        float pv = p;                       // this lane's candidate (own expert)
        for (int k = 0; k < TOPK; ++k) {
            float v = pv; int widx = lane;
            #pragma unroll
            for (int off = 32; off; off >>= 1) {
                float ov = __shfl_xor(v, off);
                int oi = __shfl_xor(widx, off);
                if (ov > v || (ov == v && oi < widx)) { v = ov; widx = oi; }
            }
            if (lane == widx) {
                int pos = atomicAdd(&cnt[lane], 1);
                if (pos < CAP) { tok_of[lane * CAP + pos] = t; sc_of[lane * CAP + pos] = p; }
                pv = -1.0f;
            }
        }
    }
    sred[wv][lane] = psum_local;
    __syncthreads();
    if (wv == 0) {
        float tot = sred[0][lane] + sred[1][lane] + sred[2][lane] + sred[3][lane];
        atomicAdd(&prob_sum[lane], tot);
    }
}

// --------------------------------------------------------------- stats ------
__global__ void stats_kernel(const int* __restrict__ cnt, const float* __restrict__ prob_sum,
                             int* __restrict__ off, int* __restrict__ d_total_tiles,
                             int* __restrict__ tile_expert, float* __restrict__ out_tail)
{
    __shared__ int soff[66];
    __shared__ float sfp[64];
    const int tid = threadIdx.x;
    if (tid == 0) {
        int o = 0;
        for (int e = 0; e < NEXP; ++e) {
            soff[e] = o;
            int c = cnt[e]; if (c > CAP) c = CAP;
            o += ((c + 127) >> 7) << 7;          // 128-align each expert
        }
        soff[64] = o;                            // shared expert (count T_TOKENS)
        soff[65] = o + T_TOKENS;
        *d_total_tiles = (o + T_TOKENS) >> 7;
    }
    __syncthreads();
    if (tid < 66) off[tid] = soff[tid];
    const int total = soff[65] >> 7;
    for (int tile = tid; tile < MAXTILES; tile += blockDim.x) {
        if (tile < total) {
            int e = 0;
            for (int q = 1; q < 65; ++q) if (soff[q] <= tile * 128) e = q;
            tile_expert[tile] = e;
        }
    }
    if (tid < 64) {
        float f  = (float)cnt[tid] * (1.0f / 24576.0f);
        float pr = prob_sum[tid] * (1.0f / 4096.0f);
        out_tail[1 + tid] = f;
        out_tail[1 + 64 + tid] = pr;
        sfp[tid] = f * pr;
    }
    __syncthreads();
    if (tid == 0) {
        float l = 0.f;
        for (int e = 0; e < NEXP; ++e) l += sfp[e];
        out_tail[0] = 0.01f * l;
    }
}

// -------------------------------------------------------------- gather ------
__global__ __launch_bounds__(192)
void gather_kernel(const float* __restrict__ x,
                   const int* __restrict__ off, const int* __restrict__ cnt,
                   const int* __restrict__ tile_expert, const int* __restrict__ d_total_tiles,
                   const int* __restrict__ tok_of, const float* __restrict__ sc_of,
                   ushort* __restrict__ Xg, int* __restrict__ row_tok, float* __restrict__ row_score)
{
    const int row = blockIdx.x;
    if (row >= (*d_total_tiles) * 128) return;
    const int e = tile_expert[row >> 7];
    const int r = row - off[e];
    int t = 0; float sc = 0.f; bool real = false;
    if (e == NEXP) { t = r; sc = 1.0f; real = true; }
    else {
        int c = cnt[e]; if (c > CAP) c = CAP;
        if (r < c) { t = tok_of[e * CAP + r]; sc = sc_of[e * CAP + r]; real = true; }
    }
    const int tid = threadIdx.x;                 // 192 threads x float4 = 768
    ushort4* dst = (ushort4*)(Xg + (size_t)row * 768);
    if (real) {
        float4 v = ((const float4*)(x + (size_t)t * 768))[tid];
        ushort4 o; o.x = f2bf(v.x); o.y = f2bf(v.y); o.z = f2bf(v.z); o.w = f2bf(v.w);
        dst[tid] = o;
    } else {
        dst[tid] = make_ushort4(0, 0, 0, 0);
    }
    if (tid == 0) { row_tok[row] = t; row_score[row] = real ? sc : 0.0f; }
}

// ---------------------------------------------------------------- gemm ------
// C[128m x 128n] = act(A @ W^T + b); A bf16 [rows,KD], W fp32 [ND,KD] row-major.
// Changes vs prev: (1) XCD-chunked tile swizzle so same-expert tiles share an
// XCD's L2 for W reuse; (2) k+1 register prefetch of A+W issued during MFMA
// phase (T14 split) so HBM latency hides under compute; (3) 3 blocks/CU.
template<int KD, int ND, bool DOGELU>
__global__ __launch_bounds__(256, 3)
void gemm_kernel(const ushort* __restrict__ Abuf,
                 const float* __restrict__ Wexp, const float* __restrict__ Wsh,
                 const float* __restrict__ Bexp, const float* __restrict__ Bsh,
                 const int* __restrict__ d_total_tiles, const int* __restrict__ tile_expert,
                 ushort* __restrict__ Hout, float* __restrict__ Cout,
                 const int* __restrict__ row_tok, const float* __restrict__ row_score)
{
    // bijective swizzle within each n-round: 288 = 8 XCDs x 36-tile chunks.
    // consecutive blockIdx.x round-robin across XCDs -> XCD x gets contiguous
    // tiles [x*36, x*36+36), so same-expert tiles (sorted) share its L2.
    const int mt = (blockIdx.x & 7) * (MAXTILES / 8) + (blockIdx.x >> 3);
    if (mt >= *d_total_tiles) return;
    const int e = tile_expert[mt];
    const float* W  = (e < NEXP) ? (Wexp + (size_t)e * ND * KD) : Wsh;
    const float* Bi = (e < NEXP) ? (Bexp + (size_t)e * ND) : Bsh;
    const int row0 = mt * 128;
    const int n0 = blockIdx.y * 128;

    __shared__ ushort sA[128][72];   // BK=64, +8 pad (16B-aligned rows, 144B stride)
    __shared__ ushort sB[128][72];

    const int tid = threadIdx.x;
    const int lane = tid & 63;
    const int wv = tid >> 6;
    const int wm = (wv >> 1) << 6;
    const int wn = (wv & 1) << 6;
    const int lm = lane & 15;
    const int lq = lane >> 4;

    // staging geometry: thread owns rows rb+32c (c=0..3), 8-elem chunk at c8.
    const int rb = tid >> 3;          // 0..31
    const int c8 = (tid & 7) << 3;    // 0,8,..,56 (elements)

    const ushort* Ap = Abuf + (size_t)(row0 + rb) * KD + c8;
    const float*  Wp = W    + (size_t)(n0   + rb) * KD + c8;

    f32x4 acc[4][4] = {};
    uint4  apf[4];                    // prefetched A (bf16x8 per chunk)
    float4 wpf[8];                    // prefetched W (fp32, 2 x float4 per chunk)

    constexpr int NK = KD / 64;

    #pragma unroll
    for (int c = 0; c < 4; ++c) {     // prologue: prefetch k-step 0
        apf[c]       = *(const uint4*) (Ap + (size_t)c * 32 * KD);
        wpf[2*c]     = *(const float4*)(Wp + (size_t)c * 32 * KD);
        wpf[2*c + 1] = *(const float4*)(Wp + (size_t)c * 32 * KD + 4);
    }

    for (int ks = 0; ks < NK; ++ks) {
        // ---- write phase: drain prefetch regs into LDS (convert W here) ----
        #pragma unroll
        for (int c = 0; c < 4; ++c) {
            *(uint4*)&sA[rb + 32 * c][c8] = apf[c];
            float4 wa = wpf[2*c], wb = wpf[2*c + 1];
            uint4 u;
            u.x = pkbf(wa.x, wa.y); u.y = pkbf(wa.z, wa.w);
            u.z = pkbf(wb.x, wb.y); u.w = pkbf(wb.z, wb.w);
            *(uint4*)&sB[rb + 32 * c][c8] = u;
        }
        __syncthreads();
        // ---- issue next k-step's loads; they fly during the MFMA phase ----
        if (ks + 1 < NK) {
            const int k0 = (ks + 1) * 64;
            #pragma unroll
            for (int c = 0; c < 4; ++c) {
                apf[c]       = *(const uint4*) (Ap + (size_t)c * 32 * KD + k0);
                wpf[2*c]     = *(const float4*)(Wp + (size_t)c * 32 * KD + k0);
                wpf[2*c + 1] = *(const float4*)(Wp + (size_t)c * 32 * KD + k0 + 4);
            }
        }
        // ---- compute phase ----
        #pragma unroll
        for (int kk = 0; kk < 2; ++kk) {
            bf16x8 af[4], bfr[4];
            #pragma unroll
            for (int i = 0; i < 4; ++i)
                af[i] = *(const bf16x8*)&sA[wm + i * 16 + lm][kk * 32 + lq * 8];
            #pragma unroll
            for (int j = 0; j < 4; ++j)
                bfr[j] = *(const bf16x8*)&sB[wn + j * 16 + lm][kk * 32 + lq * 8];
            #pragma unroll
            for (int i = 0; i < 4; ++i)
                #pragma unroll
                for (int j = 0; j < 4; ++j)
                    acc[i][j] = __builtin_amdgcn_mfma_f32_16x16x32_bf16(af[i], bfr[j], acc[i][j], 0, 0, 0);
        }
        __syncthreads();
    }

    if constexpr (DOGELU) {
        #pragma unroll
        for (int i = 0; i < 4; ++i) {
            int gm = row0 + wm + i * 16 + lq * 4;
            #pragma unroll
            for (int j = 0; j < 4; ++j) {
                int gn = n0 + wn + j * 16 + lm;
                float bb = Bi[gn];
                #pragma unroll
                for (int r = 0; r < 4; ++r) {
                    float v = acc[i][j][r] + bb;
                    v = 0.5f * v * (1.0f + erff(v * 0.70710678118654752f));  // exact gelu
                    Hout[(size_t)(gm + r) * ND + gn] = f2bf(v);
                }
            }
        }
    } else {
        #pragma unroll
        for (int i = 0; i < 4; ++i) {
            int gmb = row0 + wm + i * 16 + lq * 4;
            #pragma unroll
            for (int r = 0; r < 4; ++r) {
                int gm = gmb + r;
                float sc = row_score[gm];
                if (sc != 0.0f) {
                    int t = row_tok[gm];
                    float* dst = Cout + (size_t)t * D_DIM;
                    #pragma unroll
                    for (int j = 0; j < 4; ++j) {
                        int gn = n0 + wn + j * 16 + lm;
                        float v = (acc[i][j][r] + Bi[gn]) * sc;
                        atomicAdd(dst + gn, v);
                    }
                }
            }
        }
    }
}

// -------------------------------------------------------------- launch ------
extern "C" void kernel_launch(void* const* d_in, const int* in_sizes, int n_in,
                              void* d_out, int out_size, void* d_ws, size_t ws_size,
                              hipStream_t stream)
{
    const float* x      = (const float*)d_in[0];
    const float* gate_w = (const float*)d_in[1];
    const float* sh1_w  = (const float*)d_in[2];
    const float* sh1_b  = (const float*)d_in[3];
    const float* sh2_w  = (const float*)d_in[4];
    const float* sh2_b  = (const float*)d_in[5];
    const float* e1_w   = (const float*)d_in[6];
    const float* e1_b   = (const float*)d_in[7];
    const float* e2_w   = (const float*)d_in[8];
    const float* e2_b   = (const float*)d_in[9];
    float* out = (float*)d_out;

    char* ws = (char*)d_ws;
    int*    cnt       = (int*)(ws + 0);                       // 65 ints
    float*  prob_sum  = (float*)(ws + 1024);                  // 64 f
    int*    off       = (int*)(ws + 2048);                    // 66 ints
    int*    total_t   = (int*)(ws + 3072);                    // 1 int
    int*    tile_exp  = (int*)(ws + 4096);                    // 288 ints
    int*    tok_of    = (int*)(ws + 8192);                    // 64*1536 ints
    float*  sc_of     = (float*)(ws + 8192 + (size_t)64 * CAP * 4);
    int*    row_tok   = (int*)(ws + 8192 + (size_t)2 * 64 * CAP * 4);
    float*  row_score = (float*)(ws + 8192 + (size_t)2 * 64 * CAP * 4 + (size_t)MAXROWS * 4);
    ushort* Xg        = (ushort*)(ws + (size_t)2 * 1024 * 1024);                      // 56.6 MB
    ushort* Hbuf      = (ushort*)(ws + (size_t)2 * 1024 * 1024 + (size_t)MAXROWS * 768 * 2); // 113 MB

    hipMemsetAsync(ws, 0, 2048, stream);                       // cnt + prob_sum
    hipMemsetAsync(d_out, 0, (size_t)out_size * 4, stream);    // accumulation target

    gate_kernel<<<T_TOKENS / 16, 256, 0, stream>>>(x, gate_w, cnt, prob_sum, tok_of, sc_of);
    stats_kernel<<<1, 256, 0, stream>>>(cnt, prob_sum, off, total_t, tile_exp, out + (size_t)T_TOKENS * D_DIM);
    gather_kernel<<<MAXROWS, 192, 0, stream>>>(x, off, cnt, tile_exp, total_t, tok_of, sc_of, Xg, row_tok, row_score);

    dim3 g1(MAXTILES, H_DIM / 128);
    gemm_kernel<D_DIM, H_DIM, true><<<g1, 256, 0, stream>>>(
        Xg, e1_w, sh1_w, e1_b, sh1_b, total_t, tile_exp, Hbuf, nullptr, nullptr, nullptr);

    dim3 g2(MAXTILES, D_DIM / 128);
    gemm_kernel<H_DIM, D_DIM, false><<<g2, 256, 0, stream>>>(
        Hbuf, e2_w, sh2_w, e2_b, sh2_b, total_t, tile_exp, nullptr, out, row_tok, row_score);
}

// Round 2
// 1445.197 us; speedup vs baseline: 1.0014x; 1.0014x over previous
//
#include <hip/hip_runtime.h>
#include <stdint.h>

#define T_TOKENS 4096
#define D_DIM 768
#define H_DIM 1536
#define NEXP 64
#define TOPK 6
#define CAP 1536
#define MAXTILES 288          // bound: (24576 + 64*127 + 4096)/128 = 287.5
#define MAXROWS (MAXTILES*128)

typedef __bf16 bf16x8 __attribute__((ext_vector_type(8)));
typedef float f32x4 __attribute__((ext_vector_type(4)));

__device__ __forceinline__ ushort f2bf(float f) {
    union { float f; uint32_t u; } v; v.f = f;
    uint32_t r = v.u + 0x7FFFu + ((v.u >> 16) & 1u);   // RNE
    return (ushort)(r >> 16);
}

__device__ __forceinline__ uint32_t pkbf(float lo, float hi) {
    return (uint32_t)f2bf(lo) | ((uint32_t)f2bf(hi) << 16);
}

// ---------------------------------------------------------------- gate ------
__global__ __launch_bounds__(256)
void gate_kernel(const float* __restrict__ x, const float* __restrict__ gate_w,
                 int* __restrict__ cnt, float* __restrict__ prob_sum,
                 int* __restrict__ tok_of, float* __restrict__ sc_of)
{
    __shared__ float xs[16 * 768];
    __shared__ float sred[4][64];
    const int tid = threadIdx.x;
    const int t0 = blockIdx.x * 16;
    const float4* xg = (const float4*)(x + (size_t)t0 * 768);
    float4* xs4w = (float4*)xs;
    #pragma unroll
    for (int c = 0; c < 12; ++c) xs4w[c * 256 + tid] = xg[c * 256 + tid];
    __syncthreads();
    const int lane = tid & 63;
    const int wv = tid >> 6;
    float dots[4] = {0.f, 0.f, 0.f, 0.f};
    const float4* w4 = (const float4*)(gate_w + (size_t)lane * 768);
    const float4* xs4 = (const float4*)xs;
    for (int d = 0; d < 192; ++d) {
        float4 w = w4[d];
        #pragma unroll
        for (int tt = 0; tt < 4; ++tt) {
            float4 xv = xs4[(wv * 4 + tt) * 192 + d];
            dots[tt] += w.x * xv.x + w.y * xv.y + w.z * xv.z + w.w * xv.w;
        }
    }
    float psum_local = 0.f;
    for (int tt = 0; tt < 4; ++tt) {
        const int t = t0 + wv * 4 + tt;
        float z = dots[tt];
        float m = z;
        #pragma unroll
        for (int off = 32; off; off >>= 1) m = fmaxf(m, __shfl_xor(m, off));
        float ex = expf(z - m);
        float s = ex;
        #pragma unroll
        for (int off = 32; off; off >>= 1) s += __shfl_xor(s, off);
        float p = ex / s;
        psum_local += p;
        float pv = p;                       // this lane's candidate (own expert)
        for (int k = 0; k < TOPK; ++k) {
            float v = pv; int widx = lane;
            #pragma unroll
            for (int off = 32; off; off >>= 1) {
                float ov = __shfl_xor(v, off);
                int oi = __shfl_xor(widx, off);
                if (ov > v || (ov == v && oi < widx)) { v = ov; widx = oi; }
            }
            if (lane == widx) {
                int pos = atomicAdd(&cnt[lane], 1);
                if (pos < CAP) { tok_of[lane * CAP + pos] = t; sc_of[lane * CAP + pos] = p; }
                pv = -1.0f;
            }
        }
    }
    sred[wv][lane] = psum_local;
    __syncthreads();
    if (wv == 0) {
        float tot = sred[0][lane] + sred[1][lane] + sred[2][lane] + sred[3][lane];
        atomicAdd(&prob_sum[lane], tot);
    }
}

// --------------------------------------------------------------- stats ------
__global__ void stats_kernel(const int* __restrict__ cnt, const float* __restrict__ prob_sum,
                             int* __restrict__ off, int* __restrict__ d_total_tiles,
                             int* __restrict__ tile_expert, float* __restrict__ out_tail)
{
    __shared__ int soff[66];
    __shared__ float sfp[64];
    const int tid = threadIdx.x;
    if (tid == 0) {
        int o = 0;
        for (int e = 0; e < NEXP; ++e) {
            soff[e] = o;
            int c = cnt[e]; if (c > CAP) c = CAP;
            o += ((c + 127) >> 7) << 7;          // 128-align each expert
        }
        soff[64] = o;                            // shared expert (count T_TOKENS)
        soff[65] = o + T_TOKENS;
        *d_total_tiles = (o + T_TOKENS) >> 7;
    }
    __syncthreads();
    if (tid < 66) off[tid] = soff[tid];
    const int total = soff[65] >> 7;
    for (int tile = tid; tile < MAXTILES; tile += blockDim.x) {
        if (tile < total) {
            int e = 0;
            for (int q = 1; q < 65; ++q) if (soff[q] <= tile * 128) e = q;
            tile_expert[tile] = e;
        }
    }
    if (tid < 64) {
        float f  = (float)cnt[tid] * (1.0f / 24576.0f);
        float pr = prob_sum[tid] * (1.0f / 4096.0f);
        out_tail[1 + tid] = f;
        out_tail[1 + 64 + tid] = pr;
        sfp[tid] = f * pr;
    }
    __syncthreads();
    if (tid == 0) {
        float l = 0.f;
        for (int e = 0; e < NEXP; ++e) l += sfp[e];
        out_tail[0] = 0.01f * l;
    }
}

// -------------------------------------------------------------- gather ------
__global__ __launch_bounds__(192)
void gather_kernel(const float* __restrict__ x,
                   const int* __restrict__ off, const int* __restrict__ cnt,
                   const int* __restrict__ tile_expert, const int* __restrict__ d_total_tiles,
                   const int* __restrict__ tok_of, const float* __restrict__ sc_of,
                   ushort* __restrict__ Xg, int* __restrict__ row_tok, float* __restrict__ row_score)
{
    const int row = blockIdx.x;
    if (row >= (*d_total_tiles) * 128) return;
    const int e = tile_expert[row >> 7];
    const int r = row - off[e];
    int t = 0; float sc = 0.f; bool real = false;
    if (e == NEXP) { t = r; sc = 1.0f; real = true; }
    else {
        int c = cnt[e]; if (c > CAP) c = CAP;
        if (r < c) { t = tok_of[e * CAP + r]; sc = sc_of[e * CAP + r]; real = true; }
    }
    const int tid = threadIdx.x;                 // 192 threads x float4 = 768
    ushort4* dst = (ushort4*)(Xg + (size_t)row * 768);
    if (real) {
        float4 v = ((const float4*)(x + (size_t)t * 768))[tid];
        ushort4 o; o.x = f2bf(v.x); o.y = f2bf(v.y); o.z = f2bf(v.z); o.w = f2bf(v.w);
        dst[tid] = o;
    } else {
        dst[tid] = make_ushort4(0, 0, 0, 0);
    }
    if (tid == 0) { row_tok[row] = t; row_score[row] = real ? sc : 0.0f; }
}

// ---------------------------------------------------------------- gemm ------
// C[128m x 128n] = act(A @ W^T + b); A bf16 [rows,KD], W fp32 [ND,KD] row-major.
// R2: keep XCD-chunked swizzle (r1: FETCH 654->506 MB) + k+1 register
// prefetch, but back at __launch_bounds__(256,2): r1's (256,3) capped VGPRs
// at ~170 and spilled the 48 prefetch regs to scratch (WRITE_SIZE 86->479MB).
// (256,2) caps at 256 regs: acc 64 + prefetch 48 + frags/addr fits, no spill.
template<int KD, int ND, bool DOGELU>
__global__ __launch_bounds__(256, 2)
void gemm_kernel(const ushort* __restrict__ Abuf,
                 const float* __restrict__ Wexp, const float* __restrict__ Wsh,
                 const float* __restrict__ Bexp, const float* __restrict__ Bsh,
                 const int* __restrict__ d_total_tiles, const int* __restrict__ tile_expert,
                 ushort* __restrict__ Hout, float* __restrict__ Cout,
                 const int* __restrict__ row_tok, const float* __restrict__ row_score)
{
    // bijective swizzle within each n-round: 288 = 8 XCDs x 36-tile chunks.
    const int mt = (blockIdx.x & 7) * (MAXTILES / 8) + (blockIdx.x >> 3);
    if (mt >= *d_total_tiles) return;
    const int e = tile_expert[mt];
    const float* W  = (e < NEXP) ? (Wexp + (size_t)e * ND * KD) : Wsh;
    const float* Bi = (e < NEXP) ? (Bexp + (size_t)e * ND) : Bsh;
    const int row0 = mt * 128;
    const int n0 = blockIdx.y * 128;

    __shared__ ushort sA[128][72];   // BK=64, +8 pad (16B-aligned rows, 144B stride)
    __shared__ ushort sB[128][72];

    const int tid = threadIdx.x;
    const int lane = tid & 63;
    const int wv = tid >> 6;
    const int wm = (wv >> 1) << 6;
    const int wn = (wv & 1) << 6;
    const int lm = lane & 15;
    const int lq = lane >> 4;

    // staging geometry: thread owns rows rb+32c (c=0..3), 8-elem chunk at c8.
    const int rb = tid >> 3;          // 0..31
    const int c8 = (tid & 7) << 3;    // 0,8,..,56 (elements)

    const ushort* Ap = Abuf + (size_t)(row0 + rb) * KD + c8;
    const float*  Wp = W    + (size_t)(n0   + rb) * KD + c8;

    f32x4 acc[4][4] = {};
    uint4  apf[4];                    // prefetched A (bf16x8 per chunk)
    float4 wpf[8];                    // prefetched W (fp32, 2 x float4 per chunk)

    constexpr int NK = KD / 64;

    #pragma unroll
    for (int c = 0; c < 4; ++c) {     // prologue: prefetch k-step 0
        apf[c]       = *(const uint4*) (Ap + (size_t)c * 32 * KD);
        wpf[2*c]     = *(const float4*)(Wp + (size_t)c * 32 * KD);
        wpf[2*c + 1] = *(const float4*)(Wp + (size_t)c * 32 * KD + 4);
    }

    for (int ks = 0; ks < NK; ++ks) {
        // ---- write phase: drain prefetch regs into LDS (convert W here) ----
        #pragma unroll
        for (int c = 0; c < 4; ++c) {
            *(uint4*)&sA[rb + 32 * c][c8] = apf[c];
            float4 wa = wpf[2*c], wb = wpf[2*c + 1];
            uint4 u;
            u.x = pkbf(wa.x, wa.y); u.y = pkbf(wa.z, wa.w);
            u.z = pkbf(wb.x, wb.y); u.w = pkbf(wb.z, wb.w);
            *(uint4*)&sB[rb + 32 * c][c8] = u;
        }
        __syncthreads();
        // ---- issue next k-step's loads; they fly during the MFMA phase ----
        if (ks + 1 < NK) {
            const int k0 = (ks + 1) * 64;
            #pragma unroll
            for (int c = 0; c < 4; ++c) {
                apf[c]       = *(const uint4*) (Ap + (size_t)c * 32 * KD + k0);
                wpf[2*c]     = *(const float4*)(Wp + (size_t)c * 32 * KD + k0);
                wpf[2*c + 1] = *(const float4*)(Wp + (size_t)c * 32 * KD + k0 + 4);
            }
        }
        // ---- compute phase ----
        #pragma unroll
        for (int kk = 0; kk < 2; ++kk) {
            bf16x8 af[4], bfr[4];
            #pragma unroll
            for (int i = 0; i < 4; ++i)
                af[i] = *(const bf16x8*)&sA[wm + i * 16 + lm][kk * 32 + lq * 8];
            #pragma unroll
            for (int j = 0; j < 4; ++j)
                bfr[j] = *(const bf16x8*)&sB[wn + j * 16 + lm][kk * 32 + lq * 8];
            #pragma unroll
            for (int i = 0; i < 4; ++i)
                #pragma unroll
                for (int j = 0; j < 4; ++j)
                    acc[i][j] = __builtin_amdgcn_mfma_f32_16x16x32_bf16(af[i], bfr[j], acc[i][j], 0, 0, 0);
        }
        __syncthreads();
    }

    if constexpr (DOGELU) {
        #pragma unroll
        for (int i = 0; i < 4; ++i) {
            int gm = row0 + wm + i * 16 + lq * 4;
            #pragma unroll
            for (int j = 0; j < 4; ++j) {
                int gn = n0 + wn + j * 16 + lm;
                float bb = Bi[gn];
                #pragma unroll
                for (int r = 0; r < 4; ++r) {
                    float v = acc[i][j][r] + bb;
                    v = 0.5f * v * (1.0f + erff(v * 0.70710678118654752f));  // exact gelu
                    Hout[(size_t)(gm + r) * ND + gn] = f2bf(v);
                }
            }
        }
    } else {
        #pragma unroll
        for (int i = 0; i < 4; ++i) {
            int gmb = row0 + wm + i * 16 + lq * 4;
            #pragma unroll
            for (int r = 0; r < 4; ++r) {
                int gm = gmb + r;
                float sc = row_score[gm];
                if (sc != 0.0f) {
                    int t = row_tok[gm];
                    float* dst = Cout + (size_t)t * D_DIM;
                    #pragma unroll
                    for (int j = 0; j < 4; ++j) {
                        int gn = n0 + wn + j * 16 + lm;
                        float v = (acc[i][j][r] + Bi[gn]) * sc;
                        atomicAdd(dst + gn, v);
                    }
                }
            }
        }
    }
}

// -------------------------------------------------------------- launch ------
extern "C" void kernel_launch(void* const* d_in, const int* in_sizes, int n_in,
                              void* d_out, int out_size, void* d_ws, size_t ws_size,
                              hipStream_t stream)
{
    const float* x      = (const float*)d_in[0];
    const float* gate_w = (const float*)d_in[1];
    const float* sh1_w  = (const float*)d_in[2];
    const float* sh1_b  = (const float*)d_in[3];
    const float* sh2_w  = (const float*)d_in[4];
    const float* sh2_b  = (const float*)d_in[5];
    const float* e1_w   = (const float*)d_in[6];
    const float* e1_b   = (const float*)d_in[7];
    const float* e2_w   = (const float*)d_in[8];
    const float* e2_b   = (const float*)d_in[9];
    float* out = (float*)d_out;

    char* ws = (char*)d_ws;
    int*    cnt       = (int*)(ws + 0);                       // 65 ints
    float*  prob_sum  = (float*)(ws + 1024);                  // 64 f
    int*    off       = (int*)(ws + 2048);                    // 66 ints
    int*    total_t   = (int*)(ws + 3072);                    // 1 int
    int*    tile_exp  = (int*)(ws + 4096);                    // 288 ints
    int*    tok_of    = (int*)(ws + 8192);                    // 64*1536 ints
    float*  sc_of     = (float*)(ws + 8192 + (size_t)64 * CAP * 4);
    int*    row_tok   = (int*)(ws + 8192 + (size_t)2 * 64 * CAP * 4);
    float*  row_score = (float*)(ws + 8192 + (size_t)2 * 64 * CAP * 4 + (size_t)MAXROWS * 4);
    ushort* Xg        = (ushort*)(ws + (size_t)2 * 1024 * 1024);                      // 56.6 MB
    ushort* Hbuf      = (ushort*)(ws + (size_t)2 * 1024 * 1024 + (size_t)MAXROWS * 768 * 2); // 113 MB

    hipMemsetAsync(ws, 0, 2048, stream);                       // cnt + prob_sum
    hipMemsetAsync(d_out, 0, (size_t)out_size * 4, stream);    // accumulation target

    gate_kernel<<<T_TOKENS / 16, 256, 0, stream>>>(x, gate_w, cnt, prob_sum, tok_of, sc_of);
    stats_kernel<<<1, 256, 0, stream>>>(cnt, prob_sum, off, total_t, tile_exp, out + (size_t)T_TOKENS * D_DIM);
    gather_kernel<<<MAXROWS, 192, 0, stream>>>(x, off, cnt, tile_exp, total_t, tok_of, sc_of, Xg, row_tok, row_score);

    dim3 g1(MAXTILES, H_DIM / 128);
    gemm_kernel<D_DIM, H_DIM, true><<<g1, 256, 0, stream>>>(
        Xg, e1_w, sh1_w, e1_b, sh1_b, total_t, tile_exp, Hbuf, nullptr, nullptr, nullptr);

    dim3 g2(MAXTILES, D_DIM / 128);
    gemm_kernel<H_DIM, D_DIM, false><<<g2, 256, 0, stream>>>(
        Hbuf, e2_w, sh2_w, e2_b, sh2_b, total_t, tile_exp, nullptr, out, row_tok, row_score);
}

// Round 3
// 1129.315 us; speedup vs baseline: 1.2815x; 1.2797x over previous
//
#include <hip/hip_runtime.h>
#include <stdint.h>

#define T_TOKENS 4096
#define D_DIM 768
#define H_DIM 1536
#define NEXP 64
#define TOPK 6
#define CAP 1536
#define MAXTILES 288          // bound: (24576 + 64*127 + 4096)/128 = 287.5
#define MAXROWS (MAXTILES*128)

typedef __bf16 bf16x8 __attribute__((ext_vector_type(8)));
typedef float f32x4 __attribute__((ext_vector_type(4)));

__device__ __forceinline__ ushort f2bf(float f) {
    union { float f; uint32_t u; } v; v.f = f;
    uint32_t r = v.u + 0x7FFFu + ((v.u >> 16) & 1u);   // RNE
    return (ushort)(r >> 16);
}

// ---------------------------------------------------------------- gate ------
__global__ __launch_bounds__(256)
void gate_kernel(const float* __restrict__ x, const float* __restrict__ gate_w,
                 int* __restrict__ cnt, float* __restrict__ prob_sum,
                 int* __restrict__ tok_of, float* __restrict__ sc_of)
{
    __shared__ float xs[16 * 768];
    __shared__ float sred[4][64];
    const int tid = threadIdx.x;
    const int t0 = blockIdx.x * 16;
    const float4* xg = (const float4*)(x + (size_t)t0 * 768);
    float4* xs4w = (float4*)xs;
    #pragma unroll
    for (int c = 0; c < 12; ++c) xs4w[c * 256 + tid] = xg[c * 256 + tid];
    __syncthreads();
    const int lane = tid & 63;
    const int wv = tid >> 6;
    float dots[4] = {0.f, 0.f, 0.f, 0.f};
    const float4* w4 = (const float4*)(gate_w + (size_t)lane * 768);
    const float4* xs4 = (const float4*)xs;
    for (int d = 0; d < 192; ++d) {
        float4 w = w4[d];
        #pragma unroll
        for (int tt = 0; tt < 4; ++tt) {
            float4 xv = xs4[(wv * 4 + tt) * 192 + d];
            dots[tt] += w.x * xv.x + w.y * xv.y + w.z * xv.z + w.w * xv.w;
        }
    }
    float psum_local = 0.f;
    for (int tt = 0; tt < 4; ++tt) {
        const int t = t0 + wv * 4 + tt;
        float z = dots[tt];
        float m = z;
        #pragma unroll
        for (int off = 32; off; off >>= 1) m = fmaxf(m, __shfl_xor(m, off));
        float ex = expf(z - m);
        float s = ex;
        #pragma unroll
        for (int off = 32; off; off >>= 1) s += __shfl_xor(s, off);
        float p = ex / s;
        psum_local += p;
        float pv = p;                       // this lane's candidate (own expert)
        for (int k = 0; k < TOPK; ++k) {
            float v = pv; int widx = lane;
            #pragma unroll
            for (int off = 32; off; off >>= 1) {
                float ov = __shfl_xor(v, off);
                int oi = __shfl_xor(widx, off);
                if (ov > v || (ov == v && oi < widx)) { v = ov; widx = oi; }
            }
            if (lane == widx) {
                int pos = atomicAdd(&cnt[lane], 1);
                if (pos < CAP) { tok_of[lane * CAP + pos] = t; sc_of[lane * CAP + pos] = p; }
                pv = -1.0f;
            }
        }
    }
    sred[wv][lane] = psum_local;
    __syncthreads();
    if (wv == 0) {
        float tot = sred[0][lane] + sred[1][lane] + sred[2][lane] + sred[3][lane];
        atomicAdd(&prob_sum[lane], tot);
    }
}

// --------------------------------------------------------------- stats ------
__global__ void stats_kernel(const int* __restrict__ cnt, const float* __restrict__ prob_sum,
                             int* __restrict__ off, int* __restrict__ d_total_tiles,
                             int* __restrict__ tile_expert, float* __restrict__ out_tail)
{
    __shared__ int soff[66];
    __shared__ float sfp[64];
    const int tid = threadIdx.x;
    if (tid == 0) {
        int o = 0;
        for (int e = 0; e < NEXP; ++e) {
            soff[e] = o;
            int c = cnt[e]; if (c > CAP) c = CAP;
            o += ((c + 127) >> 7) << 7;          // 128-align each expert
        }
        soff[64] = o;                            // shared expert (count T_TOKENS)
        soff[65] = o + T_TOKENS;
        *d_total_tiles = (o + T_TOKENS) >> 7;
    }
    __syncthreads();
    if (tid < 66) off[tid] = soff[tid];
    const int total = soff[65] >> 7;
    for (int tile = tid; tile < MAXTILES; tile += blockDim.x) {
        if (tile < total) {
            int e = 0;
            for (int q = 1; q < 65; ++q) if (soff[q] <= tile * 128) e = q;
            tile_expert[tile] = e;
        }
    }
    if (tid < 64) {
        float f  = (float)cnt[tid] * (1.0f / 24576.0f);
        float pr = prob_sum[tid] * (1.0f / 4096.0f);
        out_tail[1 + tid] = f;
        out_tail[1 + 64 + tid] = pr;
        sfp[tid] = f * pr;
    }
    __syncthreads();
    if (tid == 0) {
        float l = 0.f;
        for (int e = 0; e < NEXP; ++e) l += sfp[e];
        out_tail[0] = 0.01f * l;
    }
}

// -------------------------------------------------------------- rowmap ------
// Builds per-row token/score map (replaces the old gather kernel's bookkeeping;
// the data movement itself is fused into gemm1's A-staging).
__global__ __launch_bounds__(256)
void rowmap_kernel(const int* __restrict__ off, const int* __restrict__ cnt,
                   const int* __restrict__ tile_expert, const int* __restrict__ d_total_tiles,
                   const int* __restrict__ tok_of, const float* __restrict__ sc_of,
                   int* __restrict__ row_tok, float* __restrict__ row_score)
{
    const int row = blockIdx.x * 256 + threadIdx.x;
    if (row >= (*d_total_tiles) * 128) return;
    const int e = tile_expert[row >> 7];
    const int r = row - off[e];
    int t = -1; float sc = 0.f;
    if (e == NEXP) { t = r; sc = 1.0f; }
    else {
        int c = cnt[e]; if (c > CAP) c = CAP;
        if (r < c) { t = tok_of[e * CAP + r]; sc = sc_of[e * CAP + r]; }
    }
    row_tok[row] = t;
    row_score[row] = sc;
}

// ---------------------------------------------------------------- gemm ------
// C[128m x 128n] = act(A @ W^T + b); W fp32 [ND,KD] row-major.
// GATHERX=true: A rows gathered from fp32 x via row_tok (t<0 -> zero row).
// GATHERX=false: A bf16 [rows,KD] dense (Hbuf).
// R3 structure: 512 threads, 8 waves x (64x32) sub-tiles, BK=32.
// Rationale: r0 was latency-bound at ~3 waves/SIMD (80 VGPR + 64 AGPR acc in
// the unified file). Shrinking per-wave acc to 32 + frags to 24 + staging to
// 16 regs targets 4-5 waves/SIMD, doubling latency tolerance. No cross-barrier
// register prefetch (r1/r2: compiler spills it to scratch, +395MB writes).
template<int KD, int ND, bool DOGELU, bool GATHERX>
__global__ __launch_bounds__(512, 2)
void gemm_kernel(const ushort* __restrict__ Abuf, const float* __restrict__ Xsrc,
                 const float* __restrict__ Wexp, const float* __restrict__ Wsh,
                 const float* __restrict__ Bexp, const float* __restrict__ Bsh,
                 const int* __restrict__ d_total_tiles, const int* __restrict__ tile_expert,
                 ushort* __restrict__ Hout, float* __restrict__ Cout,
                 const int* __restrict__ row_tok, const float* __restrict__ row_score)
{
    // bijective XCD swizzle: 288 = 8 XCDs x 36-tile chunks (r1: FETCH 654->506MB)
    const int mt = (blockIdx.x & 7) * (MAXTILES / 8) + (blockIdx.x >> 3);
    if (mt >= *d_total_tiles) return;
    const int e = tile_expert[mt];
    const float* W  = (e < NEXP) ? (Wexp + (size_t)e * ND * KD) : Wsh;
    const float* Bi = (e < NEXP) ? (Bexp + (size_t)e * ND) : Bsh;
    const int row0 = mt * 128;
    const int n0 = blockIdx.y * 128;

    __shared__ ushort sA[128][40];   // BK=32, +8 pad (80B row stride)
    __shared__ ushort sB[128][40];

    const int tid = threadIdx.x;
    const int lane = tid & 63;
    const int wv = tid >> 6;          // 0..7
    const int wm = (wv >> 2) << 6;    // {0,64}
    const int wn = (wv & 3) << 5;     // {0,32,64,96}
    const int lm = lane & 15;
    const int lq = lane >> 4;

    // staging geometry (512 threads):
    const int rb = tid >> 3;          // 0..63 (rows rb, rb+64)
    const int c4 = (tid & 7) << 2;    // f32 col 0,4,..,28

    const float* Wp = W + (size_t)(n0 + rb) * KD + c4;

    const float* xp[2];
    const ushort* Ap = nullptr;
    int ar = 0, ac8 = 0;
    if constexpr (GATHERX) {
        #pragma unroll
        for (int c = 0; c < 2; ++c) {
            int t = row_tok[row0 + rb + 64 * c];
            xp[c] = (t >= 0) ? (Xsrc + (size_t)t * KD + c4) : nullptr;
        }
    } else {
        ar = tid >> 2;                // 0..127
        ac8 = (tid & 3) << 3;         // bf16 col 0,8,16,24
        Ap = Abuf + (size_t)(row0 + ar) * KD + ac8;
    }

    f32x4 acc[4][2] = {};
    constexpr int NK = KD / 32;

    for (int ks = 0; ks < NK; ++ks) {
        const int k0 = ks * 32;
        // ---- stage A ----
        if constexpr (GATHERX) {
            #pragma unroll
            for (int c = 0; c < 2; ++c) {
                float4 v = xp[c] ? *(const float4*)(xp[c] + k0)
                                 : make_float4(0.f, 0.f, 0.f, 0.f);
                ushort4 u;
                u.x = f2bf(v.x); u.y = f2bf(v.y); u.z = f2bf(v.z); u.w = f2bf(v.w);
                *(ushort4*)&sA[rb + 64 * c][c4] = u;
            }
        } else {
            uint4 v = *(const uint4*)(Ap + k0);
            *(uint4*)&sA[ar][ac8] = v;
        }
        // ---- stage W (fp32 -> bf16) ----
        #pragma unroll
        for (int c = 0; c < 2; ++c) {
            float4 v = *(const float4*)(Wp + (size_t)c * 64 * KD + k0);
            ushort4 u;
            u.x = f2bf(v.x); u.y = f2bf(v.y); u.z = f2bf(v.z); u.w = f2bf(v.w);
            *(ushort4*)&sB[rb + 64 * c][c4] = u;
        }
        __syncthreads();
        // ---- compute ----
        bf16x8 af[4], bfr[2];
        #pragma unroll
        for (int i = 0; i < 4; ++i)
            af[i] = *(const bf16x8*)&sA[wm + i * 16 + lm][lq * 8];
        #pragma unroll
        for (int j = 0; j < 2; ++j)
            bfr[j] = *(const bf16x8*)&sB[wn + j * 16 + lm][lq * 8];
        #pragma unroll
        for (int i = 0; i < 4; ++i)
            #pragma unroll
            for (int j = 0; j < 2; ++j)
                acc[i][j] = __builtin_amdgcn_mfma_f32_16x16x32_bf16(af[i], bfr[j], acc[i][j], 0, 0, 0);
        __syncthreads();
    }

    if constexpr (DOGELU) {
        #pragma unroll
        for (int i = 0; i < 4; ++i) {
            int gm = row0 + wm + i * 16 + lq * 4;
            #pragma unroll
            for (int j = 0; j < 2; ++j) {
                int gn = n0 + wn + j * 16 + lm;
                float bb = Bi[gn];
                #pragma unroll
                for (int r = 0; r < 4; ++r) {
                    float v = acc[i][j][r] + bb;
                    v = 0.5f * v * (1.0f + erff(v * 0.70710678118654752f));  // exact gelu
                    Hout[(size_t)(gm + r) * ND + gn] = f2bf(v);
                }
            }
        }
    } else {
        #pragma unroll
        for (int i = 0; i < 4; ++i) {
            int gmb = row0 + wm + i * 16 + lq * 4;
            #pragma unroll
            for (int r = 0; r < 4; ++r) {
                int gm = gmb + r;
                float sc = row_score[gm];
                if (sc != 0.0f) {
                    int t = row_tok[gm];
                    float* dst = Cout + (size_t)t * D_DIM;
                    #pragma unroll
                    for (int j = 0; j < 2; ++j) {
                        int gn = n0 + wn + j * 16 + lm;
                        float v = (acc[i][j][r] + Bi[gn]) * sc;
                        atomicAdd(dst + gn, v);
                    }
                }
            }
        }
    }
}

// -------------------------------------------------------------- launch ------
extern "C" void kernel_launch(void* const* d_in, const int* in_sizes, int n_in,
                              void* d_out, int out_size, void* d_ws, size_t ws_size,
                              hipStream_t stream)
{
    const float* x      = (const float*)d_in[0];
    const float* gate_w = (const float*)d_in[1];
    const float* sh1_w  = (const float*)d_in[2];
    const float* sh1_b  = (const float*)d_in[3];
    const float* sh2_w  = (const float*)d_in[4];
    const float* sh2_b  = (const float*)d_in[5];
    const float* e1_w   = (const float*)d_in[6];
    const float* e1_b   = (const float*)d_in[7];
    const float* e2_w   = (const float*)d_in[8];
    const float* e2_b   = (const float*)d_in[9];
    float* out = (float*)d_out;

    char* ws = (char*)d_ws;
    int*    cnt       = (int*)(ws + 0);                       // 65 ints
    float*  prob_sum  = (float*)(ws + 1024);                  // 64 f
    int*    off       = (int*)(ws + 2048);                    // 66 ints
    int*    total_t   = (int*)(ws + 3072);                    // 1 int
    int*    tile_exp  = (int*)(ws + 4096);                    // 288 ints
    int*    tok_of    = (int*)(ws + 8192);                    // 64*1536 ints
    float*  sc_of     = (float*)(ws + 8192 + (size_t)64 * CAP * 4);
    int*    row_tok   = (int*)(ws + 8192 + (size_t)2 * 64 * CAP * 4);
    float*  row_score = (float*)(ws + 8192 + (size_t)2 * 64 * CAP * 4 + (size_t)MAXROWS * 4);
    ushort* Hbuf      = (ushort*)(ws + (size_t)2 * 1024 * 1024);   // 113 MB (Xg removed)

    hipMemsetAsync(ws, 0, 2048, stream);                       // cnt + prob_sum
    hipMemsetAsync(d_out, 0, (size_t)out_size * 4, stream);    // accumulation target

    gate_kernel<<<T_TOKENS / 16, 256, 0, stream>>>(x, gate_w, cnt, prob_sum, tok_of, sc_of);
    stats_kernel<<<1, 256, 0, stream>>>(cnt, prob_sum, off, total_t, tile_exp, out + (size_t)T_TOKENS * D_DIM);
    rowmap_kernel<<<MAXROWS / 256, 256, 0, stream>>>(off, cnt, tile_exp, total_t, tok_of, sc_of, row_tok, row_score);

    dim3 g1(MAXTILES, H_DIM / 128);
    gemm_kernel<D_DIM, H_DIM, true, true><<<g1, 512, 0, stream>>>(
        nullptr, x, e1_w, sh1_w, e1_b, sh1_b, total_t, tile_exp, Hbuf, nullptr, row_tok, row_score);

    dim3 g2(MAXTILES, D_DIM / 128);
    gemm_kernel<H_DIM, D_DIM, false, false><<<g2, 512, 0, stream>>>(
        Hbuf, nullptr, e2_w, sh2_w, e2_b, sh2_b, total_t, tile_exp, nullptr, out, row_tok, row_score);
}